// Round 7
// baseline (22.729 us; speedup 1.0000x reference)
//
#include <hip/hip_runtime.h>
#include <stdint.h>

// Problem constants (from reference setup_inputs)
#define NVARS   128
#define EMBED   256
#define L0      1024
#define NSTEPS  16
#define NBATCH  64

typedef unsigned long long u64;
typedef unsigned int u32;
typedef u32 u32x4 __attribute__((ext_vector_type(4)));

__device__ __forceinline__ u64 shfl_xor_u64(u64 x, int m) {
    u32 lo = (u32)x, hi = (u32)(x >> 32);
    lo = __shfl_xor(lo, m, 64);
    hi = __shfl_xor(hi, m, 64);
    return ((u64)hi << 32) | (u64)lo;
}
__device__ __forceinline__ u64 shfl_u64(u64 x, int src) {
    u32 lo = (u32)x, hi = (u32)(x >> 32);
    lo = __shfl(lo, src, 64);
    hi = __shfl(hi, src, 64);
    return ((u64)hi << 32) | (u64)lo;
}

// Pack tokens [65536 rows][256 fp32 {0,1}] -> 4 u64 words/row in ws.
// 2048 blocks x 256 threads = 8192 waves (exactly chip residency: one
// full-resident pass). Wave handles 8 CONSECUTIVE rows (8 KB contiguous span);
// all 8 16-B loads issued before any ballot (128 B/lane in flight).
// Tokens are exactly 0.0f/1.0f, so load as uint4 and test bit-pattern != 0.
// Permuted bit layout (popcount/OR are permutation-invariant; output remaps):
//   word0 (A0)=lo32(m0)|lo32(m1)<<32  word1 (A1)=lo32(m2)|lo32(m3)<<32
//   word2 (B0)=hi32(m0)|hi32(m1)<<32  word3 (B1)=hi32(m2)|hi32(m3)<<32
//   (m_c = ballot of component c; lane l holds dims 4l..4l+3)
//   var v (0..127): word = 2 + ((v>>1)&1), bit = (v>>2) | ((v&1)<<5)
__global__ __launch_bounds__(256) void pack_kernel(const u32x4* __restrict__ tok4,
                                                   u64* __restrict__ packed) {
    const int lane = threadIdx.x & 63;
    const int gw   = (blockIdx.x * 256 + threadIdx.x) >> 6;   // 0..8191
    const int row0 = gw * 8;
    const u32x4* base = tok4 + (size_t)row0 * 64 + lane;

    u32x4 v[8];
    #pragma unroll
    for (int r = 0; r < 8; ++r) v[r] = base[(size_t)r * 64];

    #pragma unroll
    for (int r = 0; r < 8; ++r) {
        u64 m0 = __ballot(v[r].x != 0u);
        u64 m1 = __ballot(v[r].y != 0u);
        u64 m2 = __ballot(v[r].z != 0u);
        u64 m3 = __ballot(v[r].w != 0u);
        u64 wd;
        if      (lane == 0) wd = (m0 & 0xffffffffull) | (m1 << 32);
        else if (lane == 1) wd = (m2 & 0xffffffffull) | (m3 << 32);
        else if (lane == 2) wd = (m0 >> 32) | (m1 & 0xffffffff00000000ull);
        else                wd = (m2 >> 32) | (m3 & 0xffffffff00000000ull);
        if (lane < 4) packed[(size_t)(row0 + r) * 4 + lane] = wd;
    }
}

// ONE WAVE per batch item (64 blocks x 64 threads): zero barriers, zero LDS.
// Lane owns 16 rows (i*64+lane) in registers (~128 VGPR).
// Step 0: full min + tie-OR reduction via 6-stage shfl_xor butterfly (the merge
//   is a semilattice op, so every lane ends with the exact full reduction).
// Steps 1..15: incremental fast path — appended query rows have a==0 so cmin==0
//   always and their b-masks are subsets of the running union; counts updated
//   exactly by popcount(a & delta); rows at count 0 OR their b-bits in.
// Fixpoint early-out: if the union stops growing, counts can never change again
//   -> all remaining steps produce identical output; fill and return.
__global__ __launch_bounds__(64) void steps_kernel(const u64* __restrict__ packed,
                                                   float* __restrict__ out) {
    const int b    = blockIdx.x;
    const int lane = threadIdx.x;          // 0..63

    u64 ra0[16], ra1[16], rb0[16], rb1[16];
    const u64* p = packed + (size_t)b * L0 * 4;
    #pragma unroll
    for (int i = 0; i < 16; ++i) {
        const u64* q = p + (size_t)(i * 64 + lane) * 4;
        ra0[i] = q[0]; ra1[i] = q[1]; rb0[i] = q[2]; rb1[i] = q[3];
    }
    // query_0 = b-half of row 1023 (i=15, lane 63)
    const u64 qb0 = shfl_u64(rb0[15], 63);
    const u64 qb1 = shfl_u64(rb1[15], 63);

    // ---- step 0: counts + full min/tie-OR butterfly ----
    int cc[16];
    int cm = 0x7fffffff; u64 o0 = 0, o1 = 0;
    #pragma unroll
    for (int i = 0; i < 16; ++i) {
        cc[i] = __popcll(ra0[i] & ~qb0) + __popcll(ra1[i] & ~qb1);
        if (cc[i] < cm)       { cm = cc[i]; o0 = rb0[i]; o1 = rb1[i]; }
        else if (cc[i] == cm) { o0 |= rb0[i]; o1 |= rb1[i]; }
    }
    #pragma unroll
    for (int m = 1; m < 64; m <<= 1) {
        int c2 = __shfl_xor(cm, m, 64);
        u64 p0 = shfl_xor_u64(o0, m), p1 = shfl_xor_u64(o1, m);
        if (c2 < cm)       { cm = c2; o0 = p0; o1 = p1; }
        else if (c2 == cm) { o0 |= p0; o1 |= p1; }
    }
    // every lane now holds the exact (cm, o0, o1)

    const float TP = 0.46211715726000974f;   // tanh(0.5)
    float* ob = out + (size_t)b * NSTEPS * NVARS;

    // step-0 output (3-way: 1.0 / +TP / -TP based on pure r_0 and qb)
    {
        const int v1 = lane, v2 = lane + 64;
        const int wi1 = (v1 >> 1) & 1, bit1 = (v1 >> 2) | ((v1 & 1) << 5);
        const int wi2 = (v2 >> 1) & 1, bit2 = (v2 >> 2) | ((v2 & 1) << 5);
        u64 rw1 = wi1 ? o1 : o0, qw1 = wi1 ? qb1 : qb0;
        u64 rw2 = wi2 ? o1 : o0, qw2 = wi2 ? qb1 : qb0;
        ob[v1] = ((rw1 >> bit1) & 1) ? 1.0f : (((qw1 >> bit1) & 1) ? TP : -TP);
        ob[v2] = ((rw2 >> bit2) & 1) ? 1.0f : (((qw2 >> bit2) & 1) ? TP : -TP);
    }

    u64 rcur0 = o0 | qb0, rcur1 = o1 | qb1;   // qb_1 (running union)
    u64 qbp0 = qb0, qbp1 = qb1;               // counts currently vs qbp

    // ---- steps 1..15 ----
    for (int s = 1; s < NSTEPS; ++s) {
        const u64 d0 = rcur0 & ~qbp0, d1 = rcur1 & ~qbp1;   // uniform across lanes
        if (d0 | d1) {
            #pragma unroll
            for (int i = 0; i < 16; ++i)
                cc[i] -= __popcll(ra0[i] & d0) + __popcll(ra1[i] & d1);
            qbp0 = rcur0; qbp1 = rcur1;
        }
        u64 nb0 = 0, nb1 = 0;
        #pragma unroll
        for (int i = 0; i < 16; ++i)
            if (cc[i] == 0) { nb0 |= rb0[i]; nb1 |= rb1[i]; }
        nb0 &= ~rcur0; nb1 &= ~rcur1;

        if (__ballot((nb0 | nb1) != 0ull)) {
            // union grows: OR-butterfly (all lanes get full union delta)
            #pragma unroll
            for (int m = 1; m < 64; m <<= 1) {
                nb0 |= shfl_xor_u64(nb0, m);
                nb1 |= shfl_xor_u64(nb1, m);
            }
            rcur0 |= nb0; rcur1 |= nb1;
            const int v1 = lane, v2 = lane + 64;
            const int wi1 = (v1 >> 1) & 1, bit1 = (v1 >> 2) | ((v1 & 1) << 5);
            const int wi2 = (v2 >> 1) & 1, bit2 = (v2 >> 2) | ((v2 & 1) << 5);
            u64 rw1 = wi1 ? rcur1 : rcur0;
            u64 rw2 = wi2 ? rcur1 : rcur0;
            // r_s >= qb_s: qb-bit set => r-bit set => 1.0; else qb-bit 0 => -TP
            ob[s * NVARS + v1] = ((rw1 >> bit1) & 1) ? 1.0f : -TP;
            ob[s * NVARS + v2] = ((rw2 >> bit2) & 1) ? 1.0f : -TP;
        } else {
            // fixpoint: union stable forever -> all remaining steps identical
            const int v1 = lane, v2 = lane + 64;
            const int wi1 = (v1 >> 1) & 1, bit1 = (v1 >> 2) | ((v1 & 1) << 5);
            const int wi2 = (v2 >> 1) & 1, bit2 = (v2 >> 2) | ((v2 & 1) << 5);
            u64 rw1 = wi1 ? rcur1 : rcur0;
            u64 rw2 = wi2 ? rcur1 : rcur0;
            float f1 = ((rw1 >> bit1) & 1) ? 1.0f : -TP;
            float f2 = ((rw2 >> bit2) & 1) ? 1.0f : -TP;
            for (int t = s; t < NSTEPS; ++t) {
                ob[t * NVARS + v1] = f1;
                ob[t * NVARS + v2] = f2;
            }
            return;
        }
    }
}

extern "C" void kernel_launch(void* const* d_in, const int* in_sizes, int n_in,
                              void* d_out, int out_size, void* d_ws, size_t ws_size,
                              hipStream_t stream) {
    const u32x4* tok4 = (const u32x4*)d_in[0];
    float* out = (float*)d_out;
    u64* packed = (u64*)d_ws;   // 2 MiB of the workspace

    pack_kernel<<<2048, 256, 0, stream>>>(tok4, packed);
    steps_kernel<<<NBATCH, 64, 0, stream>>>(packed, out);
}

// Round 8
// 20.911 us; speedup vs baseline: 1.0869x; 1.0869x over previous
//
#include <hip/hip_runtime.h>
#include <stdint.h>

// Problem constants (from reference setup_inputs)
#define NVARS   128
#define EMBED   256
#define L0      1024
#define NSTEPS  16
#define NBATCH  64

typedef unsigned long long u64;
typedef unsigned int u32;
typedef u32 u32x4 __attribute__((ext_vector_type(4)));

__device__ __forceinline__ u64 shfl_xor_u64(u64 x, int m) {
    u32 lo = (u32)x, hi = (u32)(x >> 32);
    lo = __shfl_xor(lo, m, 64);
    hi = __shfl_xor(hi, m, 64);
    return ((u64)hi << 32) | (u64)lo;
}
__device__ __forceinline__ u64 shfl_u64(u64 x, int src) {
    u32 lo = (u32)x, hi = (u32)(x >> 32);
    lo = __shfl(lo, src, 64);
    hi = __shfl(hi, src, 64);
    return ((u64)hi << 32) | (u64)lo;
}

// Pack tokens [65536 rows][256 fp32 {0,1}] -> 4 u64 words/row in ws.
// 4096 blocks x 256 threads (16384 waves); wave handles 4 consecutive rows;
// lane l loads uint4 = dims 4l..4l+3 via NONTEMPORAL loads (67 MB streamed
// once per replay >> 32 MB aggregate L2 -> allocation is pure pollution).
// Tokens are exactly 0.0f/1.0f so bit-pattern != 0 test suffices.
// Permuted bit layout (popcount/OR are permutation-invariant; output remaps):
//   word0 (A0)=lo32(m0)|lo32(m1)<<32  word1 (A1)=lo32(m2)|lo32(m3)<<32
//   word2 (B0)=hi32(m0)|hi32(m1)<<32  word3 (B1)=hi32(m2)|hi32(m3)<<32
//   (m_c = ballot of component c; lane l holds dims 4l..4l+3)
//   var v (0..127): word = 2 + ((v>>1)&1), bit = (v>>2) | ((v&1)<<5)
__global__ __launch_bounds__(256) void pack_kernel(const u32x4* __restrict__ tok4,
                                                   u64* __restrict__ packed) {
    const int lane = threadIdx.x & 63;
    const int gw   = (blockIdx.x * 256 + threadIdx.x) >> 6;   // 0..16383
    const int row0 = gw * 4;
    const u32x4* base = tok4 + (size_t)row0 * 64 + lane;

    u32x4 v[4];
    #pragma unroll
    for (int r = 0; r < 4; ++r) v[r] = __builtin_nontemporal_load(base + (size_t)r * 64);

    #pragma unroll
    for (int r = 0; r < 4; ++r) {
        u64 m0 = __ballot(v[r].x != 0u);
        u64 m1 = __ballot(v[r].y != 0u);
        u64 m2 = __ballot(v[r].z != 0u);
        u64 m3 = __ballot(v[r].w != 0u);
        u64 wd;
        if      (lane == 0) wd = (m0 & 0xffffffffull) | (m1 << 32);
        else if (lane == 1) wd = (m2 & 0xffffffffull) | (m3 << 32);
        else if (lane == 2) wd = (m0 >> 32) | (m1 & 0xffffffff00000000ull);
        else                wd = (m2 >> 32) | (m3 & 0xffffffff00000000ull);
        if (lane < 4) packed[(size_t)(row0 + r) * 4 + lane] = wd;
    }
}

// ONE WAVE per batch item (64 blocks x 64 threads): zero barriers, zero LDS.
// Lane owns 16 rows (i*64+lane) in registers (~128 VGPR).
// Step 0: full min + tie-OR reduction via 6-stage shfl_xor butterfly (the merge
//   is a semilattice op, so every lane ends with the exact full reduction).
// Steps 1..15: incremental fast path — appended query rows have a==0 so cmin==0
//   always and their b-masks are subsets of the running union; counts updated
//   exactly by popcount(a & delta); rows at count 0 OR their b-bits in.
// Fixpoint early-out: if the union stops growing, counts can never change again
//   -> all remaining steps produce identical output; fill and return.
__global__ __launch_bounds__(64) void steps_kernel(const u64* __restrict__ packed,
                                                   float* __restrict__ out) {
    const int b    = blockIdx.x;
    const int lane = threadIdx.x;          // 0..63

    u64 ra0[16], ra1[16], rb0[16], rb1[16];
    const u64* p = packed + (size_t)b * L0 * 4;
    #pragma unroll
    for (int i = 0; i < 16; ++i) {
        const u64* q = p + (size_t)(i * 64 + lane) * 4;
        ra0[i] = q[0]; ra1[i] = q[1]; rb0[i] = q[2]; rb1[i] = q[3];
    }
    // query_0 = b-half of row 1023 (i=15, lane 63)
    const u64 qb0 = shfl_u64(rb0[15], 63);
    const u64 qb1 = shfl_u64(rb1[15], 63);

    // ---- step 0: counts + full min/tie-OR butterfly ----
    int cc[16];
    int cm = 0x7fffffff; u64 o0 = 0, o1 = 0;
    #pragma unroll
    for (int i = 0; i < 16; ++i) {
        cc[i] = __popcll(ra0[i] & ~qb0) + __popcll(ra1[i] & ~qb1);
        if (cc[i] < cm)       { cm = cc[i]; o0 = rb0[i]; o1 = rb1[i]; }
        else if (cc[i] == cm) { o0 |= rb0[i]; o1 |= rb1[i]; }
    }
    #pragma unroll
    for (int m = 1; m < 64; m <<= 1) {
        int c2 = __shfl_xor(cm, m, 64);
        u64 p0 = shfl_xor_u64(o0, m), p1 = shfl_xor_u64(o1, m);
        if (c2 < cm)       { cm = c2; o0 = p0; o1 = p1; }
        else if (c2 == cm) { o0 |= p0; o1 |= p1; }
    }
    // every lane now holds the exact (cm, o0, o1)

    const float TP = 0.46211715726000974f;   // tanh(0.5)
    float* ob = out + (size_t)b * NSTEPS * NVARS;

    // step-0 output (3-way: 1.0 / +TP / -TP based on pure r_0 and qb)
    {
        const int v1 = lane, v2 = lane + 64;
        const int wi1 = (v1 >> 1) & 1, bit1 = (v1 >> 2) | ((v1 & 1) << 5);
        const int wi2 = (v2 >> 1) & 1, bit2 = (v2 >> 2) | ((v2 & 1) << 5);
        u64 rw1 = wi1 ? o1 : o0, qw1 = wi1 ? qb1 : qb0;
        u64 rw2 = wi2 ? o1 : o0, qw2 = wi2 ? qb1 : qb0;
        float f1 = ((rw1 >> bit1) & 1) ? 1.0f : (((qw1 >> bit1) & 1) ? TP : -TP);
        float f2 = ((rw2 >> bit2) & 1) ? 1.0f : (((qw2 >> bit2) & 1) ? TP : -TP);
        __builtin_nontemporal_store(f1, &ob[v1]);
        __builtin_nontemporal_store(f2, &ob[v2]);
    }

    u64 rcur0 = o0 | qb0, rcur1 = o1 | qb1;   // qb_1 (running union)
    u64 qbp0 = qb0, qbp1 = qb1;               // counts currently vs qbp

    // ---- steps 1..15 ----
    for (int s = 1; s < NSTEPS; ++s) {
        const u64 d0 = rcur0 & ~qbp0, d1 = rcur1 & ~qbp1;   // uniform across lanes
        if (d0 | d1) {
            #pragma unroll
            for (int i = 0; i < 16; ++i)
                cc[i] -= __popcll(ra0[i] & d0) + __popcll(ra1[i] & d1);
            qbp0 = rcur0; qbp1 = rcur1;
        }
        u64 nb0 = 0, nb1 = 0;
        #pragma unroll
        for (int i = 0; i < 16; ++i)
            if (cc[i] == 0) { nb0 |= rb0[i]; nb1 |= rb1[i]; }
        nb0 &= ~rcur0; nb1 &= ~rcur1;

        if (__ballot((nb0 | nb1) != 0ull)) {
            // union grows: OR-butterfly (all lanes get full union delta)
            #pragma unroll
            for (int m = 1; m < 64; m <<= 1) {
                nb0 |= shfl_xor_u64(nb0, m);
                nb1 |= shfl_xor_u64(nb1, m);
            }
            rcur0 |= nb0; rcur1 |= nb1;
            const int v1 = lane, v2 = lane + 64;
            const int wi1 = (v1 >> 1) & 1, bit1 = (v1 >> 2) | ((v1 & 1) << 5);
            const int wi2 = (v2 >> 1) & 1, bit2 = (v2 >> 2) | ((v2 & 1) << 5);
            u64 rw1 = wi1 ? rcur1 : rcur0;
            u64 rw2 = wi2 ? rcur1 : rcur0;
            // r_s >= qb_s: qb-bit set => r-bit set => 1.0; else qb-bit 0 => -TP
            float f1 = ((rw1 >> bit1) & 1) ? 1.0f : -TP;
            float f2 = ((rw2 >> bit2) & 1) ? 1.0f : -TP;
            __builtin_nontemporal_store(f1, &ob[s * NVARS + v1]);
            __builtin_nontemporal_store(f2, &ob[s * NVARS + v2]);
        } else {
            // fixpoint: union stable forever -> all remaining steps identical
            const int v1 = lane, v2 = lane + 64;
            const int wi1 = (v1 >> 1) & 1, bit1 = (v1 >> 2) | ((v1 & 1) << 5);
            const int wi2 = (v2 >> 1) & 1, bit2 = (v2 >> 2) | ((v2 & 1) << 5);
            u64 rw1 = wi1 ? rcur1 : rcur0;
            u64 rw2 = wi2 ? rcur1 : rcur0;
            float f1 = ((rw1 >> bit1) & 1) ? 1.0f : -TP;
            float f2 = ((rw2 >> bit2) & 1) ? 1.0f : -TP;
            for (int t = s; t < NSTEPS; ++t) {
                __builtin_nontemporal_store(f1, &ob[t * NVARS + v1]);
                __builtin_nontemporal_store(f2, &ob[t * NVARS + v2]);
            }
            return;
        }
    }
}

extern "C" void kernel_launch(void* const* d_in, const int* in_sizes, int n_in,
                              void* d_out, int out_size, void* d_ws, size_t ws_size,
                              hipStream_t stream) {
    const u32x4* tok4 = (const u32x4*)d_in[0];
    float* out = (float*)d_out;
    u64* packed = (u64*)d_ws;   // 2 MiB of the workspace

    pack_kernel<<<4096, 256, 0, stream>>>(tok4, packed);
    steps_kernel<<<NBATCH, 64, 0, stream>>>(packed, out);
}

// Round 9
// 20.818 us; speedup vs baseline: 1.0918x; 1.0045x over previous
//
#include <hip/hip_runtime.h>
#include <stdint.h>

// Problem constants (from reference setup_inputs)
#define NVARS   128
#define EMBED   256
#define L0      1024
#define NSTEPS  16
#define NBATCH  64

typedef unsigned long long u64;
typedef unsigned int u32;
typedef u32 u32x4 __attribute__((ext_vector_type(4)));

__device__ __forceinline__ u64 shfl_xor_u64(u64 x, int m) {
    u32 lo = (u32)x, hi = (u32)(x >> 32);
    lo = __shfl_xor(lo, m, 64);
    hi = __shfl_xor(hi, m, 64);
    return ((u64)hi << 32) | (u64)lo;
}
__device__ __forceinline__ u64 shfl_u64(u64 x, int src) {
    u32 lo = (u32)x, hi = (u32)(x >> 32);
    lo = __shfl(lo, src, 64);
    hi = __shfl(hi, src, 64);
    return ((u64)hi << 32) | (u64)lo;
}

// Pack tokens [65536 rows][256 fp32 {0,1}] -> 4 u64 words/row in ws.
// 2048 blocks x 256 threads (8192 waves = chip residency); wave handles 8
// CONSECUTIVE rows (8 KB span); all 8 nontemporal 16-B loads issued before any
// ballot -> 128 B/lane outstanding (deep MLP matters more for nt loads, which
// skip L2 allocation: 67 MB streamed once per replay >> 32 MB aggregate L2).
// Tokens are exactly 0.0f/1.0f so bit-pattern != 0 test suffices.
// Permuted bit layout (popcount/OR are permutation-invariant; output remaps):
//   word0 (A0)=lo32(m0)|lo32(m1)<<32  word1 (A1)=lo32(m2)|lo32(m3)<<32
//   word2 (B0)=hi32(m0)|hi32(m1)<<32  word3 (B1)=hi32(m2)|hi32(m3)<<32
//   (m_c = ballot of component c; lane l holds dims 4l..4l+3)
//   var v (0..127): word = 2 + ((v>>1)&1), bit = (v>>2) | ((v&1)<<5)
__global__ __launch_bounds__(256) void pack_kernel(const u32x4* __restrict__ tok4,
                                                   u64* __restrict__ packed) {
    const int lane = threadIdx.x & 63;
    const int gw   = (blockIdx.x * 256 + threadIdx.x) >> 6;   // 0..8191
    const int row0 = gw * 8;
    const u32x4* base = tok4 + (size_t)row0 * 64 + lane;

    u32x4 v[8];
    #pragma unroll
    for (int r = 0; r < 8; ++r)
        v[r] = __builtin_nontemporal_load(base + (size_t)r * 64);

    #pragma unroll
    for (int r = 0; r < 8; ++r) {
        u64 m0 = __ballot(v[r].x != 0u);
        u64 m1 = __ballot(v[r].y != 0u);
        u64 m2 = __ballot(v[r].z != 0u);
        u64 m3 = __ballot(v[r].w != 0u);
        u64 wd;
        if      (lane == 0) wd = (m0 & 0xffffffffull) | (m1 << 32);
        else if (lane == 1) wd = (m2 & 0xffffffffull) | (m3 << 32);
        else if (lane == 2) wd = (m0 >> 32) | (m1 & 0xffffffff00000000ull);
        else                wd = (m2 >> 32) | (m3 & 0xffffffff00000000ull);
        if (lane < 4) packed[(size_t)(row0 + r) * 4 + lane] = wd;
    }
}

// ONE WAVE per batch item (64 blocks x 64 threads): zero barriers, zero LDS.
// Lane owns 16 rows (i*64+lane) in registers (~128 VGPR).
// Step 0: full min + tie-OR reduction via 6-stage shfl_xor butterfly (the merge
//   is a semilattice op, so every lane ends with the exact full reduction).
// Steps 1..15: incremental fast path — appended query rows have a==0 so cmin==0
//   always and their b-masks are subsets of the running union; counts updated
//   exactly by popcount(a & delta); rows at count 0 OR their b-bits in.
// Fixpoint early-out: if the union stops growing, counts can never change again
//   -> all remaining steps produce identical output; fill and return.
__global__ __launch_bounds__(64) void steps_kernel(const u64* __restrict__ packed,
                                                   float* __restrict__ out) {
    const int b    = blockIdx.x;
    const int lane = threadIdx.x;          // 0..63

    u64 ra0[16], ra1[16], rb0[16], rb1[16];
    const u64* p = packed + (size_t)b * L0 * 4;
    #pragma unroll
    for (int i = 0; i < 16; ++i) {
        const u64* q = p + (size_t)(i * 64 + lane) * 4;
        ra0[i] = q[0]; ra1[i] = q[1]; rb0[i] = q[2]; rb1[i] = q[3];
    }
    // query_0 = b-half of row 1023 (i=15, lane 63)
    const u64 qb0 = shfl_u64(rb0[15], 63);
    const u64 qb1 = shfl_u64(rb1[15], 63);

    // ---- step 0: counts + full min/tie-OR butterfly ----
    int cc[16];
    int cm = 0x7fffffff; u64 o0 = 0, o1 = 0;
    #pragma unroll
    for (int i = 0; i < 16; ++i) {
        cc[i] = __popcll(ra0[i] & ~qb0) + __popcll(ra1[i] & ~qb1);
        if (cc[i] < cm)       { cm = cc[i]; o0 = rb0[i]; o1 = rb1[i]; }
        else if (cc[i] == cm) { o0 |= rb0[i]; o1 |= rb1[i]; }
    }
    #pragma unroll
    for (int m = 1; m < 64; m <<= 1) {
        int c2 = __shfl_xor(cm, m, 64);
        u64 p0 = shfl_xor_u64(o0, m), p1 = shfl_xor_u64(o1, m);
        if (c2 < cm)       { cm = c2; o0 = p0; o1 = p1; }
        else if (c2 == cm) { o0 |= p0; o1 |= p1; }
    }
    // every lane now holds the exact (cm, o0, o1)

    const float TP = 0.46211715726000974f;   // tanh(0.5)
    float* ob = out + (size_t)b * NSTEPS * NVARS;

    // step-0 output (3-way: 1.0 / +TP / -TP based on pure r_0 and qb)
    {
        const int v1 = lane, v2 = lane + 64;
        const int wi1 = (v1 >> 1) & 1, bit1 = (v1 >> 2) | ((v1 & 1) << 5);
        const int wi2 = (v2 >> 1) & 1, bit2 = (v2 >> 2) | ((v2 & 1) << 5);
        u64 rw1 = wi1 ? o1 : o0, qw1 = wi1 ? qb1 : qb0;
        u64 rw2 = wi2 ? o1 : o0, qw2 = wi2 ? qb1 : qb0;
        float f1 = ((rw1 >> bit1) & 1) ? 1.0f : (((qw1 >> bit1) & 1) ? TP : -TP);
        float f2 = ((rw2 >> bit2) & 1) ? 1.0f : (((qw2 >> bit2) & 1) ? TP : -TP);
        __builtin_nontemporal_store(f1, &ob[v1]);
        __builtin_nontemporal_store(f2, &ob[v2]);
    }

    u64 rcur0 = o0 | qb0, rcur1 = o1 | qb1;   // qb_1 (running union)
    u64 qbp0 = qb0, qbp1 = qb1;               // counts currently vs qbp

    // ---- steps 1..15 ----
    for (int s = 1; s < NSTEPS; ++s) {
        const u64 d0 = rcur0 & ~qbp0, d1 = rcur1 & ~qbp1;   // uniform across lanes
        if (d0 | d1) {
            #pragma unroll
            for (int i = 0; i < 16; ++i)
                cc[i] -= __popcll(ra0[i] & d0) + __popcll(ra1[i] & d1);
            qbp0 = rcur0; qbp1 = rcur1;
        }
        u64 nb0 = 0, nb1 = 0;
        #pragma unroll
        for (int i = 0; i < 16; ++i)
            if (cc[i] == 0) { nb0 |= rb0[i]; nb1 |= rb1[i]; }
        nb0 &= ~rcur0; nb1 &= ~rcur1;

        if (__ballot((nb0 | nb1) != 0ull)) {
            // union grows: OR-butterfly (all lanes get full union delta)
            #pragma unroll
            for (int m = 1; m < 64; m <<= 1) {
                nb0 |= shfl_xor_u64(nb0, m);
                nb1 |= shfl_xor_u64(nb1, m);
            }
            rcur0 |= nb0; rcur1 |= nb1;
            const int v1 = lane, v2 = lane + 64;
            const int wi1 = (v1 >> 1) & 1, bit1 = (v1 >> 2) | ((v1 & 1) << 5);
            const int wi2 = (v2 >> 1) & 1, bit2 = (v2 >> 2) | ((v2 & 1) << 5);
            u64 rw1 = wi1 ? rcur1 : rcur0;
            u64 rw2 = wi2 ? rcur1 : rcur0;
            // r_s >= qb_s: qb-bit set => r-bit set => 1.0; else qb-bit 0 => -TP
            float f1 = ((rw1 >> bit1) & 1) ? 1.0f : -TP;
            float f2 = ((rw2 >> bit2) & 1) ? 1.0f : -TP;
            __builtin_nontemporal_store(f1, &ob[s * NVARS + v1]);
            __builtin_nontemporal_store(f2, &ob[s * NVARS + v2]);
        } else {
            // fixpoint: union stable forever -> all remaining steps identical
            const int v1 = lane, v2 = lane + 64;
            const int wi1 = (v1 >> 1) & 1, bit1 = (v1 >> 2) | ((v1 & 1) << 5);
            const int wi2 = (v2 >> 1) & 1, bit2 = (v2 >> 2) | ((v2 & 1) << 5);
            u64 rw1 = wi1 ? rcur1 : rcur0;
            u64 rw2 = wi2 ? rcur1 : rcur0;
            float f1 = ((rw1 >> bit1) & 1) ? 1.0f : -TP;
            float f2 = ((rw2 >> bit2) & 1) ? 1.0f : -TP;
            for (int t = s; t < NSTEPS; ++t) {
                __builtin_nontemporal_store(f1, &ob[t * NVARS + v1]);
                __builtin_nontemporal_store(f2, &ob[t * NVARS + v2]);
            }
            return;
        }
    }
}

extern "C" void kernel_launch(void* const* d_in, const int* in_sizes, int n_in,
                              void* d_out, int out_size, void* d_ws, size_t ws_size,
                              hipStream_t stream) {
    const u32x4* tok4 = (const u32x4*)d_in[0];
    float* out = (float*)d_out;
    u64* packed = (u64*)d_ws;   // 2 MiB of the workspace

    pack_kernel<<<2048, 256, 0, stream>>>(tok4, packed);
    steps_kernel<<<NBATCH, 64, 0, stream>>>(packed, out);
}